// Round 3
// baseline (218.237 us; speedup 1.0000x reference)
//
#include <hip/hip_runtime.h>
#include <math.h>

// Problem shape (fixed by the reference): B=4, S=4, N=2048, D=2048
#define NB 4
#define NS 4
#define NN 2048
#define ND 2048
#define NTHREADS 256
#define SQRT_D 45.254833995939045f   // sqrt(2048)

typedef float f32x4 __attribute__((ext_vector_type(4)));

// 28 block-wide reductions, padded to 32 for the compaction butterfly:
// v[s*7+0] = ssq(x[s]);  v[s*7+1+j] = dot(x[s]*(1+gamma), w_j), j=0..4 alpha, 5 beta
__global__ __launch_bounds__(NTHREADS, 4)
void hyperconn_kernel(const float* __restrict__ residuals,
                      const float* __restrict__ gamma,
                      const float* __restrict__ w_alpha,
                      const float* __restrict__ scale_alpha,
                      const float* __restrict__ static_alpha,
                      const float* __restrict__ w_beta,
                      const float* __restrict__ scale_beta,
                      const float* __restrict__ static_beta,
                      float* __restrict__ out)
{
    __shared__ float red[4][32];   // per-wave reduced values
    __shared__ float asb[NS][6];   // [s][0..4]=alpha row, [s][5]=beta

    const int tid  = threadIdx.x;
    const int bn   = blockIdx.x;          // 0 .. NB*NN-1
    const int b    = bn >> 11;
    const int n    = bn & (NN - 1);
    const int wave = tid >> 6;
    const int lane = tid & 63;
    const int d0   = tid << 2;            // [0, 1024)
    const int d1   = d0 + (ND >> 1);      // [1024, 2048)

    const size_t row_stride = (size_t)NN * ND;
    const float* xbase = residuals + (size_t)(b * NS) * row_stride + (size_t)n * ND;

    // ---- Load the 4 rows' slices into registers (the only HBM read of x) ----
    float xa[NS][8];
#pragma unroll
    for (int s = 0; s < NS; ++s) {
        const float* r = xbase + (size_t)s * row_stride;
        *reinterpret_cast<f32x4*>(&xa[s][0]) = *reinterpret_cast<const f32x4*>(r + d0);
        *reinterpret_cast<f32x4*>(&xa[s][4]) = *reinterpret_cast<const f32x4*>(r + d1);
    }

    // ---- In-thread partials (weights amortized over all 4 rows) ----
    float v[32];
#pragma unroll
    for (int k = 0; k < 32; ++k) v[k] = 0.f;

#pragma unroll
    for (int c = 0; c < 2; ++c) {
        const int d = (c == 0) ? d0 : d1;
        f32x4 g4 = *reinterpret_cast<const f32x4*>(gamma + d);

        float xg[NS][4];
#pragma unroll
        for (int s = 0; s < NS; ++s) {
#pragma unroll
            for (int e = 0; e < 4; ++e) {
                const float xv = xa[s][c * 4 + e];
                v[s * 7 + 0] += xv * xv;
                xg[s][e] = __builtin_fmaf(xv, g4[e], xv);   // x * (1 + gamma)
            }
        }

#pragma unroll
        for (int j = 0; j < 6; ++j) {
            const float* wsrc = (j < 5) ? (w_alpha + (size_t)j * ND + d) : (w_beta + d);
            f32x4 w4 = *reinterpret_cast<const f32x4*>(wsrc);
#pragma unroll
            for (int s = 0; s < NS; ++s)
#pragma unroll
                for (int e = 0; e < 4; ++e)
                    v[s * 7 + 1 + j] = __builtin_fmaf(xg[s][e], w4[e], v[s * 7 + 1 + j]);
        }
    }

    // ---- Compaction butterfly: 32 values over 64 lanes in 32 shuffles ----
    // Level m: each lane keeps half its values, ships the other half to lane^m.
    // After 5 levels lane l holds value brev5(l&31) summed over its 32-lane half.
#pragma unroll
    for (int lev = 0; lev < 5; ++lev) {
        const int m = 1 << lev;
        const int half = 16 >> lev;
        const bool hi = (lane & m) != 0;
#pragma unroll
        for (int i = 0; i < half; ++i) {
            const float keep = hi ? v[i + half] : v[i];
            const float give = hi ? v[i] : v[i + half];
            v[i] = keep + __shfl_xor(give, m);
        }
    }
    const float tot = v[0] + __shfl_xor(v[0], 32);   // combine the two 32-lane halves
    const int idx = ((lane & 1) << 4) | ((lane & 2) << 2) | (lane & 4)
                  | ((lane & 8) >> 2) | ((lane & 16) >> 4);   // brev5(lane&31)
    if (lane < 32) red[wave][idx] = tot;
    __syncthreads();

    // ---- 24 threads: one tanh each ----
    if (tid < 24) {
        const int s = tid / 6;
        const int j = tid % 6;
        const float ssq = red[0][s * 7] + red[1][s * 7] + red[2][s * 7] + red[3][s * 7];
        const float dot = red[0][s * 7 + 1 + j] + red[1][s * 7 + 1 + j]
                        + red[2][s * 7 + 1 + j] + red[3][s * 7 + 1 + j];
        const float rs  = SQRT_D / fmaxf(sqrtf(ssq), 1e-12f);
        const float th  = tanhf(dot * rs);
        asb[s][j] = (j < 5) ? (th * scale_alpha[0] + static_alpha[s * 5 + j])
                            : (th * scale_beta[0]  + static_beta[s]);
    }
    __syncthreads();

    // ---- M[so][si] = beta[so]*alpha[si][0] + alpha[si][so+1] (broadcast LDS reads) ----
    float M[NS][NS];
#pragma unroll
    for (int so = 0; so < NS; ++so)
#pragma unroll
        for (int si = 0; si < NS; ++si)
            M[so][si] = asb[so][5] * asb[si][0] + asb[si][so + 1];

    // ---- out[so][d] = sum_si M[so][si] * x[si][d]  (nt store: out never re-read) ----
    float* obase = out + (size_t)(b * NS) * row_stride + (size_t)n * ND;
#pragma unroll
    for (int so = 0; so < NS; ++so) {
        f32x4 olo, ohi;
#pragma unroll
        for (int e = 0; e < 4; ++e) {
            olo[e] = M[so][0] * xa[0][e] + M[so][1] * xa[1][e]
                   + M[so][2] * xa[2][e] + M[so][3] * xa[3][e];
            ohi[e] = M[so][0] * xa[0][4 + e] + M[so][1] * xa[1][4 + e]
                   + M[so][2] * xa[2][4 + e] + M[so][3] * xa[3][4 + e];
        }
        float* w = obase + (size_t)so * row_stride;
        __builtin_nontemporal_store(olo, (f32x4*)(w + d0));
        __builtin_nontemporal_store(ohi, (f32x4*)(w + d1));
    }
}

extern "C" void kernel_launch(void* const* d_in, const int* in_sizes, int n_in,
                              void* d_out, int out_size, void* d_ws, size_t ws_size,
                              hipStream_t stream) {
    const float* residuals    = (const float*)d_in[0];
    const float* gamma        = (const float*)d_in[1];
    const float* w_alpha      = (const float*)d_in[2];
    const float* scale_alpha  = (const float*)d_in[3];
    const float* static_alpha = (const float*)d_in[4];
    const float* w_beta       = (const float*)d_in[5];
    const float* scale_beta   = (const float*)d_in[6];
    const float* static_beta  = (const float*)d_in[7];
    float* out = (float*)d_out;

    const int grid = NB * NN;  // 8192 blocks, one per (b, n)
    hyperconn_kernel<<<grid, NTHREADS, 0, stream>>>(
        residuals, gamma, w_alpha, scale_alpha, static_alpha,
        w_beta, scale_beta, static_beta, out);
}

// Round 4
// 192.031 us; speedup vs baseline: 1.1365x; 1.1365x over previous
//
#include <hip/hip_runtime.h>
#include <math.h>

// Problem shape (fixed by the reference): B=4, S=4, N=2048, D=2048
#define NB 4
#define NS 4
#define NN 2048
#define ND 2048
#define NTHREADS 256
#define CHUNK 4          // consecutive n-pairs per block, software-pipelined
#define SQRT_D 45.254833995939045f   // sqrt(2048)

typedef float f32x4 __attribute__((ext_vector_type(4)));

// One pipeline stage. XC = current pair's x (registers), XN = next pair's
// destination buffer. K and PREF are compile-time literals at every
// expansion site -> all array indices static, no scratch (R3 lesson).
#define PAIR(XC, XN, K, PREF)                                                \
  {                                                                          \
    /* partials: v[s*7]=ssq(x[s]); v[s*7+1+j]=dot(x[s], w_j*(1+g)) */        \
    float v[28];                                                             \
    _Pragma("unroll") for (int q = 0; q < 28; ++q) v[q] = 0.f;               \
    _Pragma("unroll") for (int c = 0; c < 2; ++c) {                          \
      const int d = (c == 0) ? d0 : d1;                                      \
      f32x4 g4 = *(const f32x4*)(gamma + d);                                 \
      _Pragma("unroll") for (int s = 0; s < NS; ++s)                         \
        _Pragma("unroll") for (int e = 0; e < 4; ++e)                        \
          v[s*7] = __builtin_fmaf(XC[s][c*4+e], XC[s][c*4+e], v[s*7]);       \
      _Pragma("unroll") for (int j = 0; j < 6; ++j) {                        \
        const float* wsrc = (j < 5) ? (w_alpha + (size_t)j*ND + d)           \
                                    : (w_beta + d);                          \
        f32x4 w4 = *(const f32x4*)wsrc;                                      \
        f32x4 wg = w4 + w4 * g4;   /* w*(1+gamma), folded per load */        \
        _Pragma("unroll") for (int s = 0; s < NS; ++s)                       \
          _Pragma("unroll") for (int e = 0; e < 4; ++e)                      \
            v[s*7+1+j] = __builtin_fmaf(XC[s][c*4+e], wg[e], v[s*7+1+j]);    \
      }                                                                      \
    }                                                                        \
    /* prefetch next pair AFTER the weight loads so their vmcnt waits     */ \
    /* don't chain on these; loads land during butterfly+barrier+apply    */ \
    if (PREF) {                                                              \
      const float* nb_ = xb + (size_t)((K) + 1) * ND;                        \
      _Pragma("unroll") for (int s = 0; s < NS; ++s) {                       \
        const float* r = nb_ + (size_t)s * row_stride;                       \
        *(f32x4*)&XN[s][0] = *(const f32x4*)(r + d0);                        \
        *(f32x4*)&XN[s][4] = *(const f32x4*)(r + d1);                        \
      }                                                                      \
    }                                                                        \
    /* R1's proven butterfly: every lane ends with all 28 wave-sums */       \
    _Pragma("unroll") for (int q = 0; q < 28; ++q) {                         \
      float t = v[q];                                                        \
      t += __shfl_xor(t, 1);  t += __shfl_xor(t, 2);                         \
      t += __shfl_xor(t, 4);  t += __shfl_xor(t, 8);                         \
      t += __shfl_xor(t, 16); t += __shfl_xor(t, 32);                        \
      v[q] = t;                                                              \
    }                                                                        \
    if (lane == 0) {                                                         \
      _Pragma("unroll") for (int q = 0; q < 28; ++q)                         \
        red[(K) & 1][wave][q] = v[q];                                        \
    }                                                                        \
    __syncthreads();   /* the ONLY barrier per pair (red is dbuf'd) */       \
    {                                                                        \
      /* per-wave epilogue: lane l<24 owns (s,j)=(l/6,l%6) */                \
      const float ssq = red[(K)&1][0][es*7] + red[(K)&1][1][es*7]            \
                      + red[(K)&1][2][es*7] + red[(K)&1][3][es*7];           \
      const int di = es*7 + 1 + ej;                                          \
      const float dot = red[(K)&1][0][di] + red[(K)&1][1][di]                \
                      + red[(K)&1][2][di] + red[(K)&1][3][di];               \
      const float rs = SQRT_D / fmaxf(sqrtf(ssq), 1e-12f);                   \
      const float aval = __builtin_fmaf(tanhf(dot * rs),                     \
                                        (ej < 5) ? sa : sb, stat);           \
      float a0[4];                                                           \
      _Pragma("unroll") for (int si = 0; si < 4; ++si)                       \
        a0[si] = __shfl(aval, si * 6);                                       \
      float* op = ob + (size_t)(K) * ND;                                     \
      _Pragma("unroll") for (int so = 0; so < 4; ++so) {                     \
        const float bso = __shfl(aval, so * 6 + 5);                          \
        float Mr[4];                                                         \
        _Pragma("unroll") for (int si = 0; si < 4; ++si)                     \
          Mr[si] = __builtin_fmaf(bso, a0[si], __shfl(aval, si*6 + so + 1)); \
        f32x4 olo, ohi;                                                      \
        _Pragma("unroll") for (int e = 0; e < 4; ++e) {                      \
          olo[e] = Mr[0]*XC[0][e]   + Mr[1]*XC[1][e]                         \
                 + Mr[2]*XC[2][e]   + Mr[3]*XC[3][e];                        \
          ohi[e] = Mr[0]*XC[0][4+e] + Mr[1]*XC[1][4+e]                       \
                 + Mr[2]*XC[2][4+e] + Mr[3]*XC[3][4+e];                      \
        }                                                                    \
        float* wp = op + (size_t)so * row_stride;                            \
        *(f32x4*)(wp + d0) = olo;                                            \
        *(f32x4*)(wp + d1) = ohi;                                            \
      }                                                                      \
    }                                                                        \
  }

__global__ __launch_bounds__(NTHREADS, 4)
void hyperconn_kernel(const float* __restrict__ residuals,
                      const float* __restrict__ gamma,
                      const float* __restrict__ w_alpha,
                      const float* __restrict__ scale_alpha,
                      const float* __restrict__ static_alpha,
                      const float* __restrict__ w_beta,
                      const float* __restrict__ scale_beta,
                      const float* __restrict__ static_beta,
                      float* __restrict__ out)
{
    __shared__ float red[2][4][28];   // double-buffered per-wave sums (896 B)

    const int tid  = threadIdx.x;
    const int blk  = blockIdx.x;             // 0..2047
    const int b    = blk >> 9;                // 512 blocks per b
    const int n0   = (blk & 511) * CHUNK;     // consecutive n chunk
    const int wave = tid >> 6;
    const int lane = tid & 63;
    const int d0   = tid << 2;                // [0,1024)
    const int d1   = d0 + (ND >> 1);          // [1024,2048)

    const size_t row_stride = (size_t)NN * ND;
    const float* xb = residuals + (size_t)(b * NS) * row_stride + (size_t)n0 * ND;
    float*       ob = out       + (size_t)(b * NS) * row_stride + (size_t)n0 * ND;

    // Hoisted per-lane epilogue constants (lane l<24 owns tanh (s,j))
    const int l24 = (lane < 24) ? lane : 0;
    const int es = l24 / 6, ej = l24 % 6;
    const float sa = scale_alpha[0], sb = scale_beta[0];
    const float stat = (ej < 5) ? static_alpha[es * 5 + ej] : static_beta[es];

    // Ping-pong register buffers for the 4 rows' slices
    float xaA[NS][8], xaB[NS][8];

    // Prologue: load pair 0
#pragma unroll
    for (int s = 0; s < NS; ++s) {
        const float* r = xb + (size_t)s * row_stride;
        *(f32x4*)&xaA[s][0] = *(const f32x4*)(r + d0);
        *(f32x4*)&xaA[s][4] = *(const f32x4*)(r + d1);
    }

    PAIR(xaA, xaB, 0, 1)
    PAIR(xaB, xaA, 1, 1)
    PAIR(xaA, xaB, 2, 1)
    PAIR(xaB, xaA, 3, 0)
}

extern "C" void kernel_launch(void* const* d_in, const int* in_sizes, int n_in,
                              void* d_out, int out_size, void* d_ws, size_t ws_size,
                              hipStream_t stream) {
    const float* residuals    = (const float*)d_in[0];
    const float* gamma        = (const float*)d_in[1];
    const float* w_alpha      = (const float*)d_in[2];
    const float* scale_alpha  = (const float*)d_in[3];
    const float* static_alpha = (const float*)d_in[4];
    const float* w_beta       = (const float*)d_in[5];
    const float* scale_beta   = (const float*)d_in[6];
    const float* static_beta  = (const float*)d_in[7];
    float* out = (float*)d_out;

    const int grid = NB * NN / CHUNK;  // 2048 blocks, CHUNK pairs each
    hyperconn_kernel<<<grid, NTHREADS, 0, stream>>>(
        residuals, gamma, w_alpha, scale_alpha, static_alpha,
        w_beta, scale_beta, static_beta, out);
}

// Round 5
// 87.805 us; speedup vs baseline: 2.4855x; 2.1870x over previous
//
#include <hip/hip_runtime.h>
#include <math.h>

// Problem shape (fixed by the reference): B=4, S=4, N=2048, D=2048
#define NB 4
#define NS 4
#define NN 2048
#define ND 2048
#define NTHREADS 256
#define SQRT_D 45.254833995939045f   // sqrt(2048)

typedef float f32x4 __attribute__((ext_vector_type(4)));

#if __has_builtin(__builtin_amdgcn_global_load_lds)
#define HAVE_DMA 1
typedef __attribute__((address_space(3))) void lds_void_t;
typedef const __attribute__((address_space(1))) void glb_void_t;
// 64 lanes x 16B -> 1KB per issue; LDS dest = wave-uniform base + lane*16
#define ASYNC_COPY16(g, l) \
    __builtin_amdgcn_global_load_lds((glb_void_t*)(g), (lds_void_t*)(l), 16, 0, 0)
#else
#define HAVE_DMA 0
#endif

// One compaction-butterfly ship with LITERAL indices (R3 lesson: any
// non-static indexing demotes the array to scratch).
#define SHIP(I, H, M_) {                                      \
    const float keep_ = hi_ ? v[(I)+(H)] : v[(I)];            \
    const float give_ = hi_ ? v[(I)] : v[(I)+(H)];            \
    v[(I)] = keep_ + __shfl_xor(give_, (M_)); }

__global__ __launch_bounds__(NTHREADS, 4)
void hyperconn_kernel(const float* __restrict__ residuals,
                      const float* __restrict__ gamma,
                      const float* __restrict__ w_alpha,
                      const float* __restrict__ scale_alpha,
                      const float* __restrict__ static_alpha,
                      const float* __restrict__ w_beta,
                      const float* __restrict__ scale_beta,
                      const float* __restrict__ static_beta,
                      float* __restrict__ out)
{
    __shared__ float lds_x[NS * ND];   // 32 KB: the 4 input rows
    __shared__ float red[4][32];       // per-wave compacted sums (idx = brev5)
    __shared__ float asb[NS][6];       // [s][0..4]=alpha row, [s][5]=beta

    const int tid  = threadIdx.x;
    const int bn   = blockIdx.x;          // 0 .. NB*NN-1
    const int b    = bn >> 11;
    const int n    = bn & (NN - 1);
    const int wave = tid >> 6;            // wave w stages row w
    const int lane = tid & 63;
    const int d0   = tid << 2;            // [0, 1024)
    const int d1   = d0 + (ND >> 1);      // [1024, 2048)

    const size_t row_stride = (size_t)NN * ND;
    const float* xrow = residuals + (size_t)(b * NS + wave) * row_stride + (size_t)n * ND;

    // ---- Stage x tile: async DMA, zero destination VGPRs, one drain at barrier ----
#if HAVE_DMA
#pragma unroll
    for (int i = 0; i < 8; ++i) {
        ASYNC_COPY16(xrow + i * 256 + lane * 4, &lds_x[wave * ND + i * 256]);
    }
#else
    {
        f32x4 t[8];
#pragma unroll
        for (int i = 0; i < 8; ++i)
            t[i] = *(const f32x4*)(xrow + i * 256 + lane * 4);
#pragma unroll
        for (int i = 0; i < 8; ++i)
            *(f32x4*)&lds_x[wave * ND + i * 256 + lane * 4] = t[i];
    }
#endif
    __syncthreads();   // emits s_waitcnt vmcnt(0): x tile resident

    // ---- Dots: each thread owns 2 x 4-float slices of ALL 4 rows ----
    // v[s*7]=ssq(x[s]); v[s*7+1+j]=dot(x[s], w_j*(1+g)); v[28..31] zero pad
    float v[32];
#pragma unroll
    for (int k = 0; k < 32; ++k) v[k] = 0.f;

#pragma unroll
    for (int c = 0; c < 2; ++c) {
        const int d = (c == 0) ? d0 : d1;
        f32x4 g4 = *(const f32x4*)(gamma + d);
        f32x4 wg[6];
#pragma unroll
        for (int j = 0; j < 6; ++j) {
            const float* wsrc = (j < 5) ? (w_alpha + (size_t)j * ND + d) : (w_beta + d);
            f32x4 w4 = *(const f32x4*)wsrc;
            wg[j] = w4 + w4 * g4;          // w * (1 + gamma)
        }
#pragma unroll
        for (int s = 0; s < NS; ++s) {
            f32x4 xs = *(const f32x4*)&lds_x[s * ND + d];   // conflict-free b128
#pragma unroll
            for (int e = 0; e < 4; ++e) {
                v[s * 7 + 0] = __builtin_fmaf(xs[e], xs[e], v[s * 7 + 0]);
#pragma unroll
                for (int j = 0; j < 6; ++j)
                    v[s * 7 + 1 + j] = __builtin_fmaf(xs[e], wg[j][e], v[s * 7 + 1 + j]);
            }
        }
    }

    // ---- Compaction butterfly: 31 swizzles + 1 xor32 (vs R1's 168) ----
    { const bool hi_ = (lane & 1) != 0;
      SHIP(0,16,1)  SHIP(1,16,1)  SHIP(2,16,1)  SHIP(3,16,1)
      SHIP(4,16,1)  SHIP(5,16,1)  SHIP(6,16,1)  SHIP(7,16,1)
      SHIP(8,16,1)  SHIP(9,16,1)  SHIP(10,16,1) SHIP(11,16,1)
      SHIP(12,16,1) SHIP(13,16,1) SHIP(14,16,1) SHIP(15,16,1) }
    { const bool hi_ = (lane & 2) != 0;
      SHIP(0,8,2) SHIP(1,8,2) SHIP(2,8,2) SHIP(3,8,2)
      SHIP(4,8,2) SHIP(5,8,2) SHIP(6,8,2) SHIP(7,8,2) }
    { const bool hi_ = (lane & 4) != 0;
      SHIP(0,4,4) SHIP(1,4,4) SHIP(2,4,4) SHIP(3,4,4) }
    { const bool hi_ = (lane & 8) != 0;
      SHIP(0,2,8) SHIP(1,2,8) }
    { const bool hi_ = (lane & 16) != 0;
      SHIP(0,1,16) }
    const float tot = v[0] + __shfl_xor(v[0], 32);
    // lane l (l<32) holds fully-reduced value brev5(l)  [HW-verified in R3]
    const int idx = ((lane & 1) << 4) | ((lane & 2) << 2) | (lane & 4)
                  | ((lane & 8) >> 2) | ((lane & 16) >> 4);
    if (lane < 32) red[wave][idx] = tot;
    __syncthreads();

    // ---- 24 threads: one tanh each ----
    if (tid < 24) {
        const int s = tid / 6;
        const int j = tid % 6;
        const float ssq = red[0][s * 7] + red[1][s * 7] + red[2][s * 7] + red[3][s * 7];
        const float dot = red[0][s * 7 + 1 + j] + red[1][s * 7 + 1 + j]
                        + red[2][s * 7 + 1 + j] + red[3][s * 7 + 1 + j];
        const float rs  = SQRT_D / fmaxf(sqrtf(ssq), 1e-12f);
        const float th  = tanhf(dot * rs);
        asb[s][j] = (j < 5) ? (th * scale_alpha[0] + static_alpha[s * 5 + j])
                            : (th * scale_beta[0]  + static_beta[s]);
    }
    __syncthreads();

    // ---- M[so][si] = beta[so]*alpha[si][0] + alpha[si][so+1] (broadcast reads) ----
    float M[NS][NS];
#pragma unroll
    for (int so = 0; so < NS; ++so)
#pragma unroll
        for (int si = 0; si < NS; ++si)
            M[so][si] = asb[so][5] * asb[si][0] + asb[si][so + 1];

    // ---- Apply: out[so][d] = sum_si M[so][si]*x[si][d], x re-read from LDS ----
    float* obase = out + (size_t)(b * NS) * row_stride + (size_t)n * ND;
#pragma unroll
    for (int c = 0; c < 2; ++c) {
        const int d = (c == 0) ? d0 : d1;
        f32x4 xs0 = *(const f32x4*)&lds_x[0 * ND + d];
        f32x4 xs1 = *(const f32x4*)&lds_x[1 * ND + d];
        f32x4 xs2 = *(const f32x4*)&lds_x[2 * ND + d];
        f32x4 xs3 = *(const f32x4*)&lds_x[3 * ND + d];
#pragma unroll
        for (int so = 0; so < NS; ++so) {
            f32x4 o;
#pragma unroll
            for (int e = 0; e < 4; ++e)
                o[e] = M[so][0] * xs0[e] + M[so][1] * xs1[e]
                     + M[so][2] * xs2[e] + M[so][3] * xs3[e];
            __builtin_nontemporal_store(o, (f32x4*)(obase + (size_t)so * row_stride + d));
        }
    }
}

extern "C" void kernel_launch(void* const* d_in, const int* in_sizes, int n_in,
                              void* d_out, int out_size, void* d_ws, size_t ws_size,
                              hipStream_t stream) {
    const float* residuals    = (const float*)d_in[0];
    const float* gamma        = (const float*)d_in[1];
    const float* w_alpha      = (const float*)d_in[2];
    const float* scale_alpha  = (const float*)d_in[3];
    const float* static_alpha = (const float*)d_in[4];
    const float* w_beta       = (const float*)d_in[5];
    const float* scale_beta   = (const float*)d_in[6];
    const float* static_beta  = (const float*)d_in[7];
    float* out = (float*)d_out;

    const int grid = NB * NN;  // 8192 blocks, one per (b, n)
    hyperconn_kernel<<<grid, NTHREADS, 0, stream>>>(
        residuals, gamma, w_alpha, scale_alpha, static_alpha,
        w_beta, scale_beta, static_beta, out);
}